// Round 10
// baseline (412.984 us; speedup 1.0000x reference)
//
#include <hip/hip_runtime.h>
#include <cstddef>

// Problem constants
#define NB 16
#define NVOX 128
#define NPT 1920
#define NBINS 32768    // 16 b * 16 tz * 16 ty * 8 tx  (tile = 16x8x8 out)
#define CH 128         // point chunk per tile block

// ---------------------------------------------------------------------------
// Stage 1: Conv1d(256,240,1) on the (256,8) view, all 16 batches.
// ---------------------------------------------------------------------------
__global__ __launch_bounds__(256)
void mlp_stage1(const float* __restrict__ q, const float* __restrict__ w1,
                const float* __restrict__ b1, float* __restrict__ x1g)
{
    __shared__ float wrow[256];
    __shared__ float psum[256];
    const int o = blockIdx.x;
    const int t = threadIdx.x;

    wrow[t] = w1[o * 256 + t];
    __syncthreads();

    const int half = t >> 7;
    const int bl = t & 127;
    const int b = bl >> 3, l = bl & 7;
    const float* qb = q + b * 2048 + l + half * 1024;
    float s = 0.f;
    #pragma unroll 8
    for (int i = 0; i < 128; ++i)
        s = fmaf(wrow[half * 128 + i], qb[i * 8], s);
    psum[t] = s;
    __syncthreads();

    if (t < 128) {
        int bb = t >> 3, ll = t & 7;
        x1g[bb * 1920 + o * 8 + ll] = b1[o] + psum[t] + psum[t + 128];
    }
}

// ---------------------------------------------------------------------------
// Bin range for 16x8x8 tiles (x 16-wide, y 8, z 8). Output span [c0-3, c0+4].
// ---------------------------------------------------------------------------
__device__ __forceinline__ void bin_range(int x0, int y0, int z0,
                                          int& txl, int& txh, int& tyl, int& tyh,
                                          int& tzl, int& tzh)
{
    txl = max(0, x0 - 3) >> 4; txh = min(127, x0 + 4) >> 4;
    tyl = max(0, y0 - 3) >> 3; tyh = min(127, y0 + 4) >> 3;
    tzl = max(0, z0 - 3) >> 3; tzh = min(127, z0 + 4) >> 3;
}

// ---------------------------------------------------------------------------
// Tail: IN chains + grouped convs + point generation + per-tile counts
// (LDS histogram, one block per batch; no global atomics).
// ---------------------------------------------------------------------------
__global__ __launch_bounds__(256)
void mlp_tail(const float* __restrict__ x1g, const float* __restrict__ qval,
              const float* __restrict__ w2, const float* __restrict__ b2,
              const float* __restrict__ w3, const float* __restrict__ b3,
              const float* __restrict__ w4, const float* __restrict__ b4,
              const float* __restrict__ w5, const float* __restrict__ b5,
              float4* __restrict__ pts, int* __restrict__ counts)
{
    __shared__ float bufA[7680];
    __shared__ float bufC[3840];
    __shared__ float psum[256], psq[256];
    __shared__ float meanv[64], rstdv[64];
    __shared__ float m4[16], r4[16];
    __shared__ int hist[2048];

    const int b = blockIdx.x;
    const int t = threadIdx.x;

    for (int u = t; u < 2048; u += 256) hist[u] = 0;
    for (int u = t; u < 1920; u += 256) bufA[u] = x1g[b * 1920 + u];
    __syncthreads();

    // IN1 over (64,30)
    {
        int c = t >> 2, g = t & 3;
        float s = 0.f, s2 = 0.f;
        for (int p = g; p < 30; p += 4) { float v = bufA[c * 30 + p]; s += v; s2 += v * v; }
        psum[t] = s; psq[t] = s2;
    }
    __syncthreads();
    if (t < 64) {
        float s = 0.f, s2 = 0.f;
        for (int g = 0; g < 4; ++g) { s += psum[t * 4 + g]; s2 += psq[t * 4 + g]; }
        float m = s * (1.f / 30.f);
        float var = s2 * (1.f / 30.f) - m * m;
        meanv[t] = m; rstdv[t] = rsqrtf(var + 1e-5f);
    }
    __syncthreads();
    for (int k = t; k < 1920; k += 256) {
        int c = k / 30;
        bufA[k] = fmaxf((bufA[k] - meanv[c]) * rstdv[c], 0.f);
    }
    __syncthreads();

    // stage2: grouped conv 64->128, flat (32,120)
    for (int m = t; m < 3840; m += 256) {
        int c = m / 60;
        int r = m - c * 60;
        int j = r / 30;
        int p = r - j * 30;
        bufC[m] = fmaf(bufA[c * 30 + p], w2[c * 2 + j], b2[c * 2 + j]);
    }
    __syncthreads();
    // IN2 over (32,120)
    {
        int c = t >> 3, g = t & 7;
        float s = 0.f, s2 = 0.f;
        for (int p = g; p < 120; p += 8) { float v = bufC[c * 120 + p]; s += v; s2 += v * v; }
        psum[t] = s; psq[t] = s2;
    }
    __syncthreads();
    if (t < 32) {
        float s = 0.f, s2 = 0.f;
        for (int g = 0; g < 8; ++g) { s += psum[t * 8 + g]; s2 += psq[t * 8 + g]; }
        float m = s * (1.f / 120.f);
        float var = s2 * (1.f / 120.f) - m * m;
        meanv[t] = m; rstdv[t] = rsqrtf(var + 1e-5f);
    }
    __syncthreads();
    for (int m = t; m < 3840; m += 256) {
        int c = m / 120;
        bufC[m] = fmaxf((bufC[m] - meanv[c]) * rstdv[c], 0.f);
    }
    __syncthreads();

    // stage3: grouped conv 32->64, flat (16,480)
    for (int m = t; m < 7680; m += 256) {
        int c = m / 240;
        int r = m - c * 240;
        int j = r / 120;
        int p = r - j * 120;
        bufA[m] = fmaf(bufC[c * 120 + p], w3[c * 2 + j], b3[c * 2 + j]);
    }
    __syncthreads();

    // IN3 over (16,480): 16 threads/channel
    const int c3 = t >> 4, g3 = t & 15;
    {
        float s = 0.f, s2 = 0.f;
        for (int k = 0; k < 30; ++k) { float v = bufA[c3 * 480 + g3 + 16 * k]; s += v; s2 += v * v; }
        psum[t] = s; psq[t] = s2;
    }
    __syncthreads();
    if (t < 16) {
        float s = 0.f, s2 = 0.f;
        for (int g = 0; g < 16; ++g) { s += psum[t * 16 + g]; s2 += psq[t * 16 + g]; }
        float m = s * (1.f / 480.f);
        float var = s2 * (1.f / 480.f) - m * m;
        meanv[t] = m; rstdv[t] = rsqrtf(var + 1e-5f);
    }
    __syncthreads();
    {
        float m = meanv[c3], r = rstdv[c3];
        float s = 0.f, s2 = 0.f;
        for (int k = 0; k < 30; ++k) {
            int idx = c3 * 480 + g3 + 16 * k;
            float v = fmaxf((bufA[idx] - m) * r, 0.f);
            bufA[idx] = v; s += v; s2 += v * v;
        }
        psum[t] = s; psq[t] = s2;
    }
    __syncthreads();
    // stage4 IN stats analytically
    if (t < 16) {
        float s = 0.f, s2 = 0.f;
        for (int g = 0; g < 16; ++g) { s += psum[t * 16 + g]; s2 += psq[t * 16 + g]; }
        float sum4 = 0.f, sq4 = 0.f;
        for (int j = 0; j < 4; ++j) {
            float w = w4[t * 4 + j], bb = b4[t * 4 + j];
            sum4 += w * s + 480.f * bb;
            sq4  += w * w * s2 + 2.f * w * bb * s + 480.f * bb * bb;
        }
        float m = sum4 * (1.f / 1920.f);
        float var = sq4 * (1.f / 1920.f) - m * m;
        m4[t] = m; r4[t] = rsqrtf(var + 1e-5f);
    }
    __syncthreads();

    // per-point: stage4 apply + stage5 + tanh + emit point + count tiles
    for (int l = t; l < NPT; l += 256) {
        int j = l / 480;
        int p = l - j * 480;
        float a0 = b5[0], a1 = b5[1], a2 = b5[2];
        #pragma unroll
        for (int c = 0; c < 16; ++c) {
            float xv = bufA[c * 480 + p];
            float x4 = fmaf(xv, w4[c * 4 + j], b4[c * 4 + j]);
            float h  = fmaxf((x4 - m4[c]) * r4[c], 0.f);
            a0 = fmaf(w5[c],      h, a0);
            a1 = fmaf(w5[16 + c], h, a1);
            a2 = fmaf(w5[32 + c], h, a2);
        }
        float px = tanhf(a0) * 64.f + 63.5f;
        float py = tanhf(a1) * 64.f + 63.5f;
        float pz = tanhf(a2) * 64.f + 63.5f;
        float val = 1.f / (1.f + expf(-qval[l]));
        float4 pv; pv.x = px; pv.y = py; pv.z = pz; pv.w = val;
        pts[b * NPT + l] = pv;

        int x0 = (int)floorf(px), y0 = (int)floorf(py), z0 = (int)floorf(pz);
        int txl, txh, tyl, tyh, tzl, tzh;
        bin_range(x0, y0, z0, txl, txh, tyl, tyh, tzl, tzh);
        for (int tz = tzl; tz <= tzh; ++tz)
            for (int ty = tyl; ty <= tyh; ++ty)
                for (int tx = txl; tx <= txh; ++tx)
                    atomicAdd(&hist[(tz * 16 + ty) * 8 + tx], 1);
    }
    __syncthreads();
    for (int u = t; u < 2048; u += 256) counts[b * 2048 + u] = hist[u];
}

// ---------------------------------------------------------------------------
// Hierarchical exclusive scan of 32768 counts (coalesced).
// ---------------------------------------------------------------------------
__global__ __launch_bounds__(256)
void scan_a(const int* __restrict__ counts, int* __restrict__ offsets,
            int* __restrict__ part)
{
    __shared__ int sd[256];
    const int t = threadIdx.x;
    const int g = blockIdx.x * 256 + t;
    int v = counts[g];
    sd[t] = v;
    __syncthreads();
    for (int off = 1; off < 256; off <<= 1) {
        int u = (t >= off) ? sd[t - off] : 0;
        __syncthreads();
        sd[t] += u;
        __syncthreads();
    }
    offsets[g] = sd[t] - v;
    if (t == 255) part[blockIdx.x] = sd[t];
}

__global__ __launch_bounds__(128)
void scan_b(int* __restrict__ part, int* __restrict__ partoff,
            int* __restrict__ offsets)
{
    __shared__ int sd[128];
    const int t = threadIdx.x;
    int v = part[t];
    sd[t] = v;
    __syncthreads();
    for (int off = 1; off < 128; off <<= 1) {
        int u = (t >= off) ? sd[t - off] : 0;
        __syncthreads();
        sd[t] += u;
        __syncthreads();
    }
    partoff[t] = sd[t] - v;
    if (t == 127) offsets[NBINS] = sd[t];
}

__global__ __launch_bounds__(256)
void scan_c(int* __restrict__ offsets, const int* __restrict__ partoff)
{
    const int g = blockIdx.x * 256 + threadIdx.x;
    offsets[g] += partoff[blockIdx.x];
}

// ---------------------------------------------------------------------------
// Scatter points into bins; cursors in LDS (one block per batch).
// ---------------------------------------------------------------------------
__global__ __launch_bounds__(256)
void bin_fill(const float4* __restrict__ pts, const int* __restrict__ offsets,
              float4* __restrict__ binned)
{
    __shared__ int cur[2048];
    const int b = blockIdx.x;
    const int t = threadIdx.x;
    for (int u = t; u < 2048; u += 256) cur[u] = offsets[b * 2048 + u];
    __syncthreads();

    for (int l = t; l < NPT; l += 256) {
        float4 pt = pts[b * NPT + l];
        int x0 = (int)floorf(pt.x), y0 = (int)floorf(pt.y), z0 = (int)floorf(pt.z);
        int txl, txh, tyl, tyh, tzl, tzh;
        bin_range(x0, y0, z0, txl, txh, tyl, tyh, tzl, tzh);
        for (int tz = tzl; tz <= tzh; ++tz)
            for (int ty = tyl; ty <= tyh; ++ty)
                for (int tx = txl; tx <= txh; ++tx) {
                    int pos = atomicAdd(&cur[(tz * 16 + ty) * 8 + tx], 1);
                    binned[pos] = pt;
                }
    }
}

// ---------------------------------------------------------------------------
// Composed 7-tap coefficient at output X for a tap at X+d (verified kernel:
// outer 1,3; inner cm1/c0/cp1 position-dependent).
// ---------------------------------------------------------------------------
__device__ __forceinline__ float stap(int X, int d)
{
    int ad = d < 0 ? -d : d;
    if (ad > 3) return 0.f;
    if (ad == 3) return 1.f;
    if (ad == 2) return 3.f;
    if (d == -1) return (X == 1 || X == 127) ? 5.f : 6.f;
    if (d == 0)  return (X == 0 || X == 127) ? 4.f : 7.f;
    return (X == 0 || X == 126) ? 5.f : 6.f;   // d == +1
}

// Per-point per-axis 8-tap table: contribution of this point's splat to
// outputs X = c0-3+o, o=0..7. Includes splat boundary clipping and 1/27.
__device__ __forceinline__ void build_tab(float* tab, int c0, float f)
{
    const bool v0 = (c0 >= 0);        // c0 <= 127 always (c0 = floor(p), p < 127.5)
    const bool v1 = (c0 + 1 <= 127);
    #pragma unroll
    for (int o = 0; o < 8; ++o) {
        int X = c0 - 3 + o;
        float v = 0.f;
        if ((unsigned)X < 128u) {
            if (v0) v += (1.f - f) * stap(X, 3 - o);
            if (v1) v += f * stap(X, 4 - o);
        }
        tab[o] = v * (1.f / 27.f);
    }
}

// ---------------------------------------------------------------------------
// Gather tile kernel: one block per 16x8x8 output region (32768 blocks,
// 256 threads; thread owns 4 consecutive x). Per chunk of <=128 binned
// points: build separable 8-tap tables in LDS, then every thread
// accumulates num/den for its 4 outputs. n==0 falls through to a zero store.
// ---------------------------------------------------------------------------
__global__ __launch_bounds__(256)
void tile_out(const float4* __restrict__ binned, const int* __restrict__ offsets,
              float* __restrict__ out)
{
    __shared__ float fxs[CH][8], fys[CH][8], fzs[CH][8];
    __shared__ int   cxs[CH], cys[CH], czs[CH];
    __shared__ float cvs[CH];

    const int code = blockIdx.x;
    const int tx   = code & 7;
    const int ty   = (code >> 3) & 15;
    const int tz   = (code >> 7) & 15;
    const int b    = code >> 11;
    const int Tx = tx * 16, Ty = ty * 8, Tz = tz * 8;
    const int t = threadIdx.x;

    const int off = offsets[code];
    const int n   = offsets[code + 1] - off;

    const int qx = t & 3, y = (t >> 2) & 7, z = t >> 5;
    const int X0 = Tx + 4 * qx, Y = Ty + y, Z = Tz + z;

    float num0 = 0.f, num1 = 0.f, num2 = 0.f, num3 = 0.f;
    float den0 = 0.f, den1 = 0.f, den2 = 0.f, den3 = 0.f;

    for (int base = 0; base < n; base += CH) {
        const int chn = min(CH, n - base);
        if (base) __syncthreads();    // protect LDS reuse across chunks
        if (t < chn) {
            float4 pt = binned[off + base + t];
            float x0f = floorf(pt.x), y0f = floorf(pt.y), z0f = floorf(pt.z);
            int x0 = (int)x0f, y0 = (int)y0f, z0 = (int)z0f;
            cxs[t] = x0; cys[t] = y0; czs[t] = z0; cvs[t] = pt.w;
            build_tab(fxs[t], x0, pt.x - x0f);
            build_tab(fys[t], y0, pt.y - y0f);
            build_tab(fzs[t], z0, pt.z - z0f);
        }
        __syncthreads();

        for (int p = 0; p < chn; ++p) {
            int oy = Y - cys[p] + 3;
            int oz = Z - czs[p] + 3;
            if ((oy | oz) & ~7) continue;            // either outside [0,8)
            float fyz  = fys[p][oy] * fzs[p][oz];
            float vfyz = cvs[p] * fyz;
            int ox0 = X0 - cxs[p] + 3;
            // xi = 0..3, ox = ox0+xi must be in [0,8)
            if ((unsigned)(ox0 + 0) < 8u) { float fv = fxs[p][ox0 + 0]; num0 = fmaf(vfyz, fv, num0); den0 = fmaf(fyz, fv, den0); }
            if ((unsigned)(ox0 + 1) < 8u) { float fv = fxs[p][ox0 + 1]; num1 = fmaf(vfyz, fv, num1); den1 = fmaf(fyz, fv, den1); }
            if ((unsigned)(ox0 + 2) < 8u) { float fv = fxs[p][ox0 + 2]; num2 = fmaf(vfyz, fv, num2); den2 = fmaf(fyz, fv, den2); }
            if ((unsigned)(ox0 + 3) < 8u) { float fv = fxs[p][ox0 + 3]; num3 = fmaf(vfyz, fv, num3); den3 = fmaf(fyz, fv, den3); }
        }
    }

    float4 res;
    res.x = num0 / (den0 + 0.001f);
    res.y = num1 / (den1 + 0.001f);
    res.z = num2 / (den2 + 0.001f);
    res.w = num3 / (den3 + 0.001f);
    float* ob = out + (((size_t)(b * NVOX + Tz) * NVOX + Ty) * NVOX + Tx);
    *(float4*)(ob + ((size_t)z * NVOX + y) * NVOX + qx * 4) = res;
}

// ---------------------------------------------------------------------------
extern "C" void kernel_launch(void* const* d_in, const int* in_sizes, int n_in,
                              void* d_out, int out_size, void* d_ws, size_t ws_size,
                              hipStream_t stream)
{
    const float* q    = (const float*)d_in[0];
    const float* qval = (const float*)d_in[1];
    const float* w1   = (const float*)d_in[2];
    const float* b1   = (const float*)d_in[3];
    const float* w2   = (const float*)d_in[4];
    const float* b2   = (const float*)d_in[5];
    const float* w3   = (const float*)d_in[6];
    const float* b3   = (const float*)d_in[7];
    const float* w4   = (const float*)d_in[8];
    const float* b4   = (const float*)d_in[9];
    const float* w5   = (const float*)d_in[10];
    const float* b5   = (const float*)d_in[11];
    float* out = (float*)d_out;

    // ws layout (bytes):
    char* wsb = (char*)d_ws;
    int*    counts  = (int*)(wsb + 0x000000);     // 32768 ints
    int*    part    = (int*)(wsb + 0x020000);     // 128 ints
    int*    partoff = (int*)(wsb + 0x020400);     // 128 ints
    int*    offsets = (int*)(wsb + 0x020800);     // 32769 ints
    float4* pts     = (float4*)(wsb + 0x041000);  // 30720 float4 (480 KB)
    float4* binned  = (float4*)(wsb + 0x0B9000);  // <=245760 float4 (3.75 MB)
    float*  x1g     = (float*)(wsb + 0x480000);   // 30720 floats

    mlp_stage1<<<240, 256, 0, stream>>>(q, w1, b1, x1g);

    mlp_tail<<<NB, 256, 0, stream>>>(x1g, qval, w2, b2, w3, b3,
                                     w4, b4, w5, b5, pts, counts);

    scan_a<<<128, 256, 0, stream>>>(counts, offsets, part);
    scan_b<<<1, 128, 0, stream>>>(part, partoff, offsets);
    scan_c<<<128, 256, 0, stream>>>(offsets, partoff);

    bin_fill<<<NB, 256, 0, stream>>>(pts, offsets, binned);

    tile_out<<<NBINS, 256, 0, stream>>>(binned, offsets, out);
}